// Round 2
// baseline (265.359 us; speedup 1.0000x reference)
//
#include <hip/hip_runtime.h>
#include <math.h>

#define NQ        14
#define DIM       16384      // 2^14
#define BATCHN    128
#define NGATES    13
#define NGEN      15
#define NOBSN     13
#define DEPTHN    4
#define INDIM     256
#define HIDDIM    256
#define ENCDIM    195
#define TCIRC     1024

// Pauli 2x2 matrices (real, imag parts). Order: I, X, Y, Z.
__constant__ float c_PR[4][2][2] = {
  {{1.f, 0.f}, {0.f, 1.f}},   // I
  {{0.f, 1.f}, {1.f, 0.f}},   // X
  {{0.f, 0.f}, {0.f, 0.f}},   // Y (real part)
  {{1.f, 0.f}, {0.f,-1.f}},   // Z
};
__constant__ float c_PI[4][2][2] = {
  {{0.f, 0.f}, {0.f, 0.f}},
  {{0.f, 0.f}, {0.f, 0.f}},
  {{0.f,-1.f}, {1.f, 0.f}},   // Y (imag part)
  {{0.f, 0.f}, {0.f, 0.f}},
};

// ---------------- encoder: enc = silu(x W1^T + b1) W2^T + b2 ----------------
__global__ void encoder_kernel(const float* __restrict__ x,
                               const float* __restrict__ W1,
                               const float* __restrict__ b1,
                               const float* __restrict__ W2,
                               const float* __restrict__ b2,
                               float* __restrict__ enc) {
  __shared__ float xrow[INDIM];
  __shared__ float hrow[HIDDIM];
  const int b = blockIdx.x, t = threadIdx.x;
  xrow[t] = x[b * INDIM + t];
  __syncthreads();
  float acc = b1[t];
  const float* w = W1 + t * INDIM;
  for (int k = 0; k < INDIM; ++k) acc = fmaf(w[k], xrow[k], acc);
  hrow[t] = acc / (1.f + expf(-acc));       // silu
  __syncthreads();
  if (t < ENCDIM) {
    float a2 = b2[t];
    const float* w2 = W2 + t * HIDDIM;
    for (int k = 0; k < HIDDIM; ++k) a2 = fmaf(w2[k], hrow[k], a2);
    enc[b * ENCDIM + t] = a2;
  }
}

// ---------------- build U = exp(i * sum_g theta_g G_g), one thread each -----
__global__ void build_u_kernel(const float* __restrict__ enc,
                               float2* __restrict__ Umats) {
  const int idx = blockIdx.x * blockDim.x + threadIdx.x;
  if (idx >= BATCHN * NGATES) return;
  const int b = idx / NGATES, g = idx % NGATES;
  const float* th = enc + b * ENCDIM + g * NGEN;

  float Ar[16], Ai[16];
  for (int i = 0; i < 16; ++i) { Ar[i] = 0.f; Ai[i] = 0.f; }
  for (int t = 0; t < NGEN; ++t) {
    const int p = t + 1;
    const int pa = p >> 2, pb = p & 3;
    const float theta = th[t];
    for (int i = 0; i < 4; ++i)
      for (int j = 0; j < 4; ++j) {
        const float ar = c_PR[pa][i >> 1][j >> 1], ai = c_PI[pa][i >> 1][j >> 1];
        const float br = c_PR[pb][i & 1][j & 1],  bi = c_PI[pb][i & 1][j & 1];
        Ar[i * 4 + j] = fmaf(theta, ar * br - ai * bi, Ar[i * 4 + j]);
        Ai[i * 4 + j] = fmaf(theta, ar * bi + ai * br, Ai[i * 4 + j]);
      }
  }

  float nrm = 0.f;
  for (int i = 0; i < 4; ++i) {
    float rs = 0.f;
    for (int j = 0; j < 4; ++j)
      rs += sqrtf(Ar[i * 4 + j] * Ar[i * 4 + j] + Ai[i * 4 + j] * Ai[i * 4 + j]);
    nrm = fmaxf(nrm, rs);
  }
  int sct = 0;
  float scale = 1.f;
  while (nrm * scale > 0.4f && sct < 30) { scale *= 0.5f; ++sct; }

  float Mr[16], Mi[16];
  for (int i = 0; i < 16; ++i) { Mr[i] = -Ai[i] * scale; Mi[i] = Ar[i] * scale; }

  float Rr[16], Ri[16];
  for (int i = 0; i < 16; ++i) { Rr[i] = (i % 5 == 0) ? 1.f : 0.f; Ri[i] = 0.f; }
  for (int k = 12; k >= 1; --k) {
    float Tr[16], Ti[16];
    const float inv = 1.f / (float)k;
    for (int i = 0; i < 4; ++i)
      for (int j = 0; j < 4; ++j) {
        float tr = 0.f, ti = 0.f;
        for (int l = 0; l < 4; ++l) {
          const float mr = Mr[i * 4 + l], mi = Mi[i * 4 + l];
          const float rr = Rr[l * 4 + j], ri = Ri[l * 4 + j];
          tr += mr * rr - mi * ri;
          ti += mr * ri + mi * rr;
        }
        Tr[i * 4 + j] = ((i == j) ? 1.f : 0.f) + inv * tr;
        Ti[i * 4 + j] = inv * ti;
      }
    for (int i = 0; i < 16; ++i) { Rr[i] = Tr[i]; Ri[i] = Ti[i]; }
  }
  for (int it = 0; it < sct; ++it) {
    float Tr[16], Ti[16];
    for (int i = 0; i < 4; ++i)
      for (int j = 0; j < 4; ++j) {
        float tr = 0.f, ti = 0.f;
        for (int l = 0; l < 4; ++l) {
          const float ar = Rr[i * 4 + l], ai = Ri[i * 4 + l];
          const float br = Rr[l * 4 + j], bi = Ri[l * 4 + j];
          tr += ar * br - ai * bi;
          ti += ar * bi + ai * br;
        }
        Tr[i * 4 + j] = tr; Ti[i * 4 + j] = ti;
      }
    for (int i = 0; i < 16; ++i) { Rr[i] = Tr[i]; Ri[i] = Ti[i]; }
  }
  for (int i = 0; i < 16; ++i)
    Umats[idx * 16 + i] = make_float2(Rr[i], Ri[i]);
}

// ================= circuit kernel: 16 amps/thread, SoA + XOR swizzle ========
// Amplitude y lives at element index E(y); E is GF(2)-linear so
// E(a|b) = E(a)^E(b) for disjoint-bit a,b. Chosen so that every pass quad
// used below is bank-conflict-free (2 lanes/bank).
__device__ __forceinline__ int Efun(int y) {
  return y ^ (((y >> 5) ^ (y >> 10)) & 31);
}
// Composed CNOT-chain permutation (verified in round 1): bit b ^= bit b+1.
__device__ __forceinline__ int sigf(int y) { return y ^ ((y >> 1) & 8191); }

// gate on k-bits (3,2): vector index = k>>2, groups r = k&3
__device__ __forceinline__ void gate_hi(const float2* __restrict__ ug,
                                        float vr[16], float vi[16]) {
  float2 u[16];
  #pragma unroll
  for (int i = 0; i < 16; ++i) u[i] = ug[i];
  #pragma unroll
  for (int r = 0; r < 4; ++r) {
    float ar[4], ai[4];
    #pragma unroll
    for (int i = 0; i < 4; ++i) {
      float sr = 0.f, si = 0.f;
      #pragma unroll
      for (int l = 0; l < 4; ++l) {
        const float2 uu = u[i * 4 + l];
        const float xr = vr[(l << 2) | r], xi = vi[(l << 2) | r];
        sr = fmaf(uu.x, xr, fmaf(-uu.y, xi, sr));
        si = fmaf(uu.x, xi, fmaf(uu.y, xr, si));
      }
      ar[i] = sr; ai[i] = si;
    }
    #pragma unroll
    for (int i = 0; i < 4; ++i) { vr[(i << 2) | r] = ar[i]; vi[(i << 2) | r] = ai[i]; }
  }
}

// gate on k-bits (1,0): vector index = k&3, groups r = k>>2
__device__ __forceinline__ void gate_lo(const float2* __restrict__ ug,
                                        float vr[16], float vi[16]) {
  float2 u[16];
  #pragma unroll
  for (int i = 0; i < 16; ++i) u[i] = ug[i];
  #pragma unroll
  for (int r = 0; r < 4; ++r) {
    float ar[4], ai[4];
    #pragma unroll
    for (int i = 0; i < 4; ++i) {
      float sr = 0.f, si = 0.f;
      #pragma unroll
      for (int l = 0; l < 4; ++l) {
        const float2 uu = u[i * 4 + l];
        const float xr = vr[(r << 2) | l], xi = vi[(r << 2) | l];
        sr = fmaf(uu.x, xr, fmaf(-uu.y, xi, sr));
        si = fmaf(uu.x, xi, fmaf(uu.y, xr, si));
      }
      ar[i] = sr; ai[i] = si;
    }
    #pragma unroll
    for (int i = 0; i < 4; ++i) { vr[(r << 2) | i] = ar[i]; vi[(r << 2) | i] = ai[i]; }
  }
}

template<int J>
__device__ __forceinline__ void ry_bit(float c, float s, float vr[16], float vi[16]) {
  #pragma unroll
  for (int k = 0; k < 16; ++k) {
    if ((k & (1 << J)) == 0) {
      const int k1 = k | (1 << J);
      const float ar = vr[k], ai = vi[k], br = vr[k1], bi = vi[k1];
      vr[k]  = fmaf(c, ar, -(s * br));
      vi[k]  = fmaf(c, ai, -(s * bi));
      vr[k1] = fmaf(s, ar, c * br);
      vi[k1] = fmaf(s, ai, c * bi);
    }
  }
}

template<int S, bool PERM>
__device__ __forceinline__ void load16(const float* __restrict__ stR,
                                       const float* __restrict__ stI,
                                       int tid, float vr[16], float vi[16]) {
  const int m = (1 << S) - 1;
  const int B = ((tid & ~m) << 4) | (tid & m);
  #pragma unroll
  for (int k = 0; k < 16; ++k) {
    const int y = B | (k << S);
    const int a = Efun(PERM ? sigf(y) : y);
    vr[k] = stR[a]; vi[k] = stI[a];
  }
}

template<int S>
__device__ __forceinline__ void store16(float* __restrict__ stR, float* __restrict__ stI,
                                        int tid, const float vr[16], const float vi[16]) {
  const int m = (1 << S) - 1;
  const int B = ((tid & ~m) << 4) | (tid & m);
  #pragma unroll
  for (int k = 0; k < 16; ++k) {
    const int a = Efun(B | (k << S));
    stR[a] = vr[k]; stI[a] = vi[k];
  }
}

template<int S, int GHI, int GLO>
__device__ __forceinline__ void su4_pass(float* stR, float* stI,
                                         const float2* __restrict__ Ush, int tid) {
  float vr[16], vi[16];
  load16<S, false>(stR, stI, tid, vr, vi);
  if (GHI >= 0) gate_hi(Ush + GHI * 16, vr, vi);
  if (GLO >= 0) gate_lo(Ush + GLO * 16, vr, vi);
  store16<S>(stR, stI, tid, vr, vi);
  __syncthreads();
}

template<int S, bool PERM, int NB>
__device__ __forceinline__ void ry_pass(float* stR, float* stI,
                                        const float* __restrict__ ryc,
                                        const float* __restrict__ rys,
                                        int tid, int d) {
  float vr[16], vi[16];
  load16<S, PERM>(stR, stI, tid, vr, vi);
  if (PERM) __syncthreads();   // reads hit other threads' write sets
  const float* rc = ryc + d * NQ;
  const float* rs = rys + d * NQ;
  if constexpr (NB == 4) {
    ry_bit<3>(rc[13 - S - 3], rs[13 - S - 3], vr, vi);
    ry_bit<2>(rc[13 - S - 2], rs[13 - S - 2], vr, vi);
  }
  ry_bit<1>(rc[13 - S - 1], rs[13 - S - 1], vr, vi);
  ry_bit<0>(rc[13 - S - 0], rs[13 - S - 0], vr, vi);
  store16<S>(stR, stI, tid, vr, vi);
  __syncthreads();
}

// observable quadratic forms; H (4x4) in LDS, vector on k-bit pairs
__device__ __forceinline__ float obs_q32(const float2* __restrict__ hp,
                                         const float vr[16], const float vi[16]) {
  float2 h[16];
  #pragma unroll
  for (int i = 0; i < 16; ++i) h[i] = hp[i];
  float acc = 0.f;
  #pragma unroll
  for (int o = 0; o < 4; ++o) {
    #pragma unroll
    for (int i = 0; i < 4; ++i) {
      float wr = 0.f, wi = 0.f;
      #pragma unroll
      for (int l = 0; l < 4; ++l) {
        const int kl = (l << 2) | o;
        const float2 hh = h[i * 4 + l];
        wr = fmaf(hh.x, vr[kl], fmaf(-hh.y, vi[kl], wr));
        wi = fmaf(hh.x, vi[kl], fmaf(hh.y, vr[kl], wi));
      }
      const int ki = (i << 2) | o;
      acc = fmaf(vr[ki], wr, fmaf(vi[ki], wi, acc));
    }
  }
  return acc;
}
__device__ __forceinline__ float obs_q21(const float2* __restrict__ hp,
                                         const float vr[16], const float vi[16]) {
  float2 h[16];
  #pragma unroll
  for (int i = 0; i < 16; ++i) h[i] = hp[i];
  float acc = 0.f;
  #pragma unroll
  for (int o = 0; o < 4; ++o) {
    #pragma unroll
    for (int i = 0; i < 4; ++i) {
      float wr = 0.f, wi = 0.f;
      #pragma unroll
      for (int l = 0; l < 4; ++l) {
        const int kl = ((o >> 1) << 3) | (l << 1) | (o & 1);
        const float2 hh = h[i * 4 + l];
        wr = fmaf(hh.x, vr[kl], fmaf(-hh.y, vi[kl], wr));
        wi = fmaf(hh.x, vi[kl], fmaf(hh.y, vr[kl], wi));
      }
      const int ki = ((o >> 1) << 3) | (i << 1) | (o & 1);
      acc = fmaf(vr[ki], wr, fmaf(vi[ki], wi, acc));
    }
  }
  return acc;
}
__device__ __forceinline__ float obs_q10(const float2* __restrict__ hp,
                                         const float vr[16], const float vi[16]) {
  float2 h[16];
  #pragma unroll
  for (int i = 0; i < 16; ++i) h[i] = hp[i];
  float acc = 0.f;
  #pragma unroll
  for (int o = 0; o < 4; ++o) {
    #pragma unroll
    for (int i = 0; i < 4; ++i) {
      float wr = 0.f, wi = 0.f;
      #pragma unroll
      for (int l = 0; l < 4; ++l) {
        const int kl = (o << 2) | l;
        const float2 hh = h[i * 4 + l];
        wr = fmaf(hh.x, vr[kl], fmaf(-hh.y, vi[kl], wr));
        wi = fmaf(hh.x, vi[kl], fmaf(hh.y, vr[kl], wi));
      }
      const int ki = (o << 2) | i;
      acc = fmaf(vr[ki], wr, fmaf(vi[ki], wi, acc));
    }
  }
  return acc;
}

__launch_bounds__(TCIRC)
__global__ void circuit_kernel(const float2* __restrict__ Umats,
                               const float* __restrict__ vp,
                               const float* __restrict__ oA,
                               const float* __restrict__ oB,
                               const float* __restrict__ oD,
                               float* __restrict__ out) {
  __shared__ float stR[DIM];                 // 64 KiB
  __shared__ float stI[DIM];                 // 64 KiB
  __shared__ float2 Ush[NGATES * 16];
  __shared__ float2 Hsh[NOBSN * 16];
  __shared__ float  ryc[DEPTHN * NQ];
  __shared__ float  rys[DEPTHN * NQ];
  __shared__ float  red[NOBSN][TCIRC / 64];

  const int b = blockIdx.x;
  const int tid = threadIdx.x;

  for (int i = tid; i < NGATES * 16; i += TCIRC)
    Ush[i] = Umats[b * NGATES * 16 + i];
  for (int i = tid; i < DEPTHN * NQ; i += TCIRC) {
    const float h = 0.5f * vp[i];
    ryc[i] = cosf(h);
    rys[i] = sinf(h);
  }
  if (tid < NOBSN) {
    const int rr[6] = {1, 2, 2, 3, 3, 3};
    const int cc[6] = {0, 0, 1, 0, 1, 2};
    float2 H[16];
    #pragma unroll
    for (int i = 0; i < 16; ++i) H[i] = make_float2(0.f, 0.f);
    for (int m = 0; m < 6; ++m) {
      const float a = oA[tid * 6 + m], bb = oB[tid * 6 + m];
      H[rr[m] * 4 + cc[m]] = make_float2(a, bb);
      H[cc[m] * 4 + rr[m]] = make_float2(a, -bb);
    }
    H[0]  = make_float2(2.f * oD[tid * 4 + 1], 0.f);
    H[5]  = make_float2(2.f * oD[tid * 4 + 2], 0.f);
    H[10] = make_float2(2.f * oD[tid * 4 + 3], 0.f);
    for (int i = 0; i < 16; ++i) Hsh[tid * 16 + i] = H[i];
  }
  for (int y = tid; y < DIM; y += TCIRC) {
    stR[y] = (y == 0) ? 1.f : 0.f;   // E(0)==0
    stI[y] = 0.f;
  }
  __syncthreads();

  // ---- SU(4) brick layer: gate idx g for even q=2m -> m, odd q=2m+1 -> 7+m
  su4_pass<10, 0,  1>(stR, stI, Ush, tid);   // q0 (bits 13,12), q2 (11,10)
  su4_pass< 6, 2,  3>(stR, stI, Ush, tid);   // q4 (9,8),  q6 (7,6)
  su4_pass< 2, 4,  5>(stR, stI, Ush, tid);   // q8 (5,4),  q10 (3,2)
  su4_pass< 0,-1,  6>(stR, stI, Ush, tid);   // q12 (1,0)
  su4_pass< 9, 7,  8>(stR, stI, Ush, tid);   // q1 (12,11), q3 (10,9)
  su4_pass< 5, 9, 10>(stR, stI, Ush, tid);   // q5 (8,7),  q7 (6,5)
  su4_pass< 1,11, 12>(stR, stI, Ush, tid);   // q9 (4,3),  q11 (2,1)

  // ---- variational depths; CNOT chain folded into next pass's reads ----
  ry_pass<10, false, 4>(stR, stI, ryc, rys, tid, 0);
  ry_pass< 6, false, 4>(stR, stI, ryc, rys, tid, 0);
  ry_pass< 2, false, 4>(stR, stI, ryc, rys, tid, 0);
  ry_pass< 0, false, 2>(stR, stI, ryc, rys, tid, 0);
  #pragma unroll 1
  for (int d = 1; d < DEPTHN; ++d) {
    ry_pass<10, true , 4>(stR, stI, ryc, rys, tid, d);  // carries perm of d-1
    ry_pass< 6, false, 4>(stR, stI, ryc, rys, tid, d);
    ry_pass< 2, false, 4>(stR, stI, ryc, rys, tid, d);
    ry_pass< 0, false, 2>(stR, stI, ryc, rys, tid, d);
  }

  // ---- observables: state in LDS is pre-perm of depth 3 -> all reads folded
  float oacc[NOBSN];
  {
    float vr[16], vi[16];
    load16<10, true>(stR, stI, tid, vr, vi);
    oacc[0] = obs_q32(Hsh + 0 * 16, vr, vi);   // bits (13,12)
    oacc[1] = obs_q21(Hsh + 1 * 16, vr, vi);   // (12,11)
    oacc[2] = obs_q10(Hsh + 2 * 16, vr, vi);   // (11,10)
  }
  {
    float vr[16], vi[16];
    load16<7, true>(stR, stI, tid, vr, vi);
    oacc[3] = obs_q32(Hsh + 3 * 16, vr, vi);   // (10,9)
    oacc[4] = obs_q21(Hsh + 4 * 16, vr, vi);   // (9,8)
    oacc[5] = obs_q10(Hsh + 5 * 16, vr, vi);   // (8,7)
  }
  {
    float vr[16], vi[16];
    load16<4, true>(stR, stI, tid, vr, vi);
    oacc[6] = obs_q32(Hsh + 6 * 16, vr, vi);   // (7,6)
    oacc[7] = obs_q21(Hsh + 7 * 16, vr, vi);   // (6,5)
    oacc[8] = obs_q10(Hsh + 8 * 16, vr, vi);   // (5,4)
  }
  {
    float vr[16], vi[16];
    load16<1, true>(stR, stI, tid, vr, vi);
    oacc[9]  = obs_q32(Hsh + 9 * 16, vr, vi);  // (4,3)
    oacc[10] = obs_q21(Hsh + 10 * 16, vr, vi); // (3,2)
    oacc[11] = obs_q10(Hsh + 11 * 16, vr, vi); // (2,1)
  }
  {
    float vr[16], vi[16];
    load16<0, true>(stR, stI, tid, vr, vi);
    oacc[12] = obs_q10(Hsh + 12 * 16, vr, vi); // (1,0)
  }

  const int lane = tid & 63, wid = tid >> 6;
  #pragma unroll
  for (int o = 0; o < NOBSN; ++o) {
    float a = oacc[o];
    #pragma unroll
    for (int off = 32; off > 0; off >>= 1)
      a += __shfl_down(a, off, 64);
    if (lane == 0) red[o][wid] = a;
  }
  __syncthreads();
  if (tid < NOBSN) {
    float s = 0.f;
    #pragma unroll
    for (int w = 0; w < TCIRC / 64; ++w) s += red[tid][w];
    out[b * NOBSN + tid] = s;
  }
}

extern "C" void kernel_launch(void* const* d_in, const int* in_sizes, int n_in,
                              void* d_out, int out_size, void* d_ws, size_t ws_size,
                              hipStream_t stream) {
  const float* x  = (const float*)d_in[0];
  const float* W1 = (const float*)d_in[1];
  const float* b1 = (const float*)d_in[2];
  const float* W2 = (const float*)d_in[3];
  const float* b2 = (const float*)d_in[4];
  const float* vp = (const float*)d_in[5];
  const float* oA = (const float*)d_in[6];
  const float* oB = (const float*)d_in[7];
  const float* oD = (const float*)d_in[8];
  float* out = (float*)d_out;

  float* enc = (float*)d_ws;
  const size_t enc_bytes = (size_t)BATCHN * ENCDIM * sizeof(float);
  float2* U = (float2*)((char*)d_ws + ((enc_bytes + 255) & ~(size_t)255));

  encoder_kernel<<<BATCHN, 256, 0, stream>>>(x, W1, b1, W2, b2, enc);
  build_u_kernel<<<(BATCHN * NGATES + 255) / 256, 256, 0, stream>>>(enc, U);
  circuit_kernel<<<BATCHN, TCIRC, 0, stream>>>(U, vp, oA, oB, oD, out);
}

// Round 3
// 255.438 us; speedup vs baseline: 1.0388x; 1.0388x over previous
//
#include <hip/hip_runtime.h>
#include <math.h>

#define NQ        14
#define DIM       16384      // 2^14
#define BATCHN    128
#define NGATES    13
#define NGEN      15
#define NOBSN     13
#define DEPTHN    4
#define INDIM     256
#define HIDDIM    256
#define ENCDIM    195
#define TCIRC     1024

// Pauli 2x2 matrices (real, imag parts). Order: I, X, Y, Z.
__constant__ float c_PR[4][2][2] = {
  {{1.f, 0.f}, {0.f, 1.f}},   // I
  {{0.f, 1.f}, {1.f, 0.f}},   // X
  {{0.f, 0.f}, {0.f, 0.f}},   // Y (real part)
  {{1.f, 0.f}, {0.f,-1.f}},   // Z
};
__constant__ float c_PI[4][2][2] = {
  {{0.f, 0.f}, {0.f, 0.f}},
  {{0.f, 0.f}, {0.f, 0.f}},
  {{0.f,-1.f}, {1.f, 0.f}},   // Y (imag part)
  {{0.f, 0.f}, {0.f, 0.f}},
};

// ---------------- encoder: enc = silu(x W1^T + b1) W2^T + b2 ----------------
__global__ void encoder_kernel(const float* __restrict__ x,
                               const float* __restrict__ W1,
                               const float* __restrict__ b1,
                               const float* __restrict__ W2,
                               const float* __restrict__ b2,
                               float* __restrict__ enc) {
  __shared__ float xrow[INDIM];
  __shared__ float hrow[HIDDIM];
  const int b = blockIdx.x, t = threadIdx.x;
  xrow[t] = x[b * INDIM + t];
  __syncthreads();
  float acc = b1[t];
  const float* w = W1 + t * INDIM;
  for (int k = 0; k < INDIM; ++k) acc = fmaf(w[k], xrow[k], acc);
  hrow[t] = acc / (1.f + expf(-acc));       // silu
  __syncthreads();
  if (t < ENCDIM) {
    float a2 = b2[t];
    const float* w2 = W2 + t * HIDDIM;
    for (int k = 0; k < HIDDIM; ++k) a2 = fmaf(w2[k], hrow[k], a2);
    enc[b * ENCDIM + t] = a2;
  }
}

// ---------------- build U = exp(i * sum_g theta_g G_g), one thread each -----
__global__ void build_u_kernel(const float* __restrict__ enc,
                               float2* __restrict__ Umats) {
  const int idx = blockIdx.x * blockDim.x + threadIdx.x;
  if (idx >= BATCHN * NGATES) return;
  const int b = idx / NGATES, g = idx % NGATES;
  const float* th = enc + b * ENCDIM + g * NGEN;

  float Ar[16], Ai[16];
  for (int i = 0; i < 16; ++i) { Ar[i] = 0.f; Ai[i] = 0.f; }
  for (int t = 0; t < NGEN; ++t) {
    const int p = t + 1;
    const int pa = p >> 2, pb = p & 3;
    const float theta = th[t];
    for (int i = 0; i < 4; ++i)
      for (int j = 0; j < 4; ++j) {
        const float ar = c_PR[pa][i >> 1][j >> 1], ai = c_PI[pa][i >> 1][j >> 1];
        const float br = c_PR[pb][i & 1][j & 1],  bi = c_PI[pb][i & 1][j & 1];
        Ar[i * 4 + j] = fmaf(theta, ar * br - ai * bi, Ar[i * 4 + j]);
        Ai[i * 4 + j] = fmaf(theta, ar * bi + ai * br, Ai[i * 4 + j]);
      }
  }

  float nrm = 0.f;
  for (int i = 0; i < 4; ++i) {
    float rs = 0.f;
    for (int j = 0; j < 4; ++j)
      rs += sqrtf(Ar[i * 4 + j] * Ar[i * 4 + j] + Ai[i * 4 + j] * Ai[i * 4 + j]);
    nrm = fmaxf(nrm, rs);
  }
  int sct = 0;
  float scale = 1.f;
  while (nrm * scale > 0.4f && sct < 30) { scale *= 0.5f; ++sct; }

  float Mr[16], Mi[16];
  for (int i = 0; i < 16; ++i) { Mr[i] = -Ai[i] * scale; Mi[i] = Ar[i] * scale; }

  float Rr[16], Ri[16];
  for (int i = 0; i < 16; ++i) { Rr[i] = (i % 5 == 0) ? 1.f : 0.f; Ri[i] = 0.f; }
  for (int k = 12; k >= 1; --k) {
    float Tr[16], Ti[16];
    const float inv = 1.f / (float)k;
    for (int i = 0; i < 4; ++i)
      for (int j = 0; j < 4; ++j) {
        float tr = 0.f, ti = 0.f;
        for (int l = 0; l < 4; ++l) {
          const float mr = Mr[i * 4 + l], mi = Mi[i * 4 + l];
          const float rr = Rr[l * 4 + j], ri = Ri[l * 4 + j];
          tr += mr * rr - mi * ri;
          ti += mr * ri + mi * rr;
        }
        Tr[i * 4 + j] = ((i == j) ? 1.f : 0.f) + inv * tr;
        Ti[i * 4 + j] = inv * ti;
      }
    for (int i = 0; i < 16; ++i) { Rr[i] = Tr[i]; Ri[i] = Ti[i]; }
  }
  for (int it = 0; it < sct; ++it) {
    float Tr[16], Ti[16];
    for (int i = 0; i < 4; ++i)
      for (int j = 0; j < 4; ++j) {
        float tr = 0.f, ti = 0.f;
        for (int l = 0; l < 4; ++l) {
          const float ar = Rr[i * 4 + l], ai = Ri[i * 4 + l];
          const float br = Rr[l * 4 + j], bi = Ri[l * 4 + j];
          tr += ar * br - ai * bi;
          ti += ar * bi + ai * br;
        }
        Tr[i * 4 + j] = tr; Ti[i * 4 + j] = ti;
      }
    for (int i = 0; i < 16; ++i) { Rr[i] = Tr[i]; Ri[i] = Ti[i]; }
  }
  for (int i = 0; i < 16; ++i)
    Umats[idx * 16 + i] = make_float2(Rr[i], Ri[i]);
}

// ================= circuit kernel: 16 amps/thread, SoA + XOR swizzle ========
// Amplitude y lives at element index E(y); E is GF(2)-linear so
// E(a|b) = E(a)^E(b) for disjoint-bit a,b. Chosen so that every pass quad
// used below is bank-conflict-free (2 lanes/bank).
__device__ __forceinline__ int Efun(int y) {
  return y ^ (((y >> 5) ^ (y >> 10)) & 31);
}
// Composed CNOT-chain permutation: bit b ^= bit b+1.
__device__ __forceinline__ int sigf(int y) { return y ^ ((y >> 1) & 8191); }

// gate on k-bits (3,2): vector index = k>>2, groups r = k&3
__device__ __forceinline__ void gate_hi(const float2* __restrict__ ug,
                                        float vr[16], float vi[16]) {
  float2 u[16];
  #pragma unroll
  for (int i = 0; i < 16; ++i) u[i] = ug[i];
  #pragma unroll
  for (int r = 0; r < 4; ++r) {
    float ar[4], ai[4];
    #pragma unroll
    for (int i = 0; i < 4; ++i) {
      float sr = 0.f, si = 0.f;
      #pragma unroll
      for (int l = 0; l < 4; ++l) {
        const float2 uu = u[i * 4 + l];
        const float xr = vr[(l << 2) | r], xi = vi[(l << 2) | r];
        sr = fmaf(uu.x, xr, fmaf(-uu.y, xi, sr));
        si = fmaf(uu.x, xi, fmaf(uu.y, xr, si));
      }
      ar[i] = sr; ai[i] = si;
    }
    #pragma unroll
    for (int i = 0; i < 4; ++i) { vr[(i << 2) | r] = ar[i]; vi[(i << 2) | r] = ai[i]; }
  }
}

// gate on k-bits (1,0): vector index = k&3, groups r = k>>2
__device__ __forceinline__ void gate_lo(const float2* __restrict__ ug,
                                        float vr[16], float vi[16]) {
  float2 u[16];
  #pragma unroll
  for (int i = 0; i < 16; ++i) u[i] = ug[i];
  #pragma unroll
  for (int r = 0; r < 4; ++r) {
    float ar[4], ai[4];
    #pragma unroll
    for (int i = 0; i < 4; ++i) {
      float sr = 0.f, si = 0.f;
      #pragma unroll
      for (int l = 0; l < 4; ++l) {
        const float2 uu = u[i * 4 + l];
        const float xr = vr[(r << 2) | l], xi = vi[(r << 2) | l];
        sr = fmaf(uu.x, xr, fmaf(-uu.y, xi, sr));
        si = fmaf(uu.x, xi, fmaf(uu.y, xr, si));
      }
      ar[i] = sr; ai[i] = si;
    }
    #pragma unroll
    for (int i = 0; i < 4; ++i) { vr[(r << 2) | i] = ar[i]; vi[(r << 2) | i] = ai[i]; }
  }
}

template<int J>
__device__ __forceinline__ void ry_bit(float c, float s, float vr[16], float vi[16]) {
  #pragma unroll
  for (int k = 0; k < 16; ++k) {
    if ((k & (1 << J)) == 0) {
      const int k1 = k | (1 << J);
      const float ar = vr[k], ai = vi[k], br = vr[k1], bi = vi[k1];
      vr[k]  = fmaf(c, ar, -(s * br));
      vi[k]  = fmaf(c, ai, -(s * bi));
      vr[k1] = fmaf(s, ar, c * br);
      vi[k1] = fmaf(s, ai, c * bi);
    }
  }
}

template<int S, bool PERM>
__device__ __forceinline__ void load16(const float* __restrict__ stR,
                                       const float* __restrict__ stI,
                                       int tid, float vr[16], float vi[16]) {
  const int m = (1 << S) - 1;
  const int B = ((tid & ~m) << 4) | (tid & m);
  #pragma unroll
  for (int k = 0; k < 16; ++k) {
    const int y = B | (k << S);
    const int a = Efun(PERM ? sigf(y) : y);
    vr[k] = stR[a]; vi[k] = stI[a];
  }
}

template<int S>
__device__ __forceinline__ void store16(float* __restrict__ stR, float* __restrict__ stI,
                                        int tid, const float vr[16], const float vi[16]) {
  const int m = (1 << S) - 1;
  const int B = ((tid & ~m) << 4) | (tid & m);
  #pragma unroll
  for (int k = 0; k < 16; ++k) {
    const int a = Efun(B | (k << S));
    stR[a] = vr[k]; stI[a] = vi[k];
  }
}

template<int S, int GHI, int GLO>
__device__ __forceinline__ void su4_pass(float* stR, float* stI,
                                         const float2* __restrict__ Ush, int tid) {
  float vr[16], vi[16];
  load16<S, false>(stR, stI, tid, vr, vi);
  if (GHI >= 0) gate_hi(Ush + GHI * 16, vr, vi);
  if (GLO >= 0) gate_lo(Ush + GLO * 16, vr, vi);
  store16<S>(stR, stI, tid, vr, vi);
  __syncthreads();
}

template<int S, bool PERM, int NB>
__device__ __forceinline__ void ry_pass(float* stR, float* stI,
                                        const float* __restrict__ ryc,
                                        const float* __restrict__ rys,
                                        int tid, int d) {
  float vr[16], vi[16];
  load16<S, PERM>(stR, stI, tid, vr, vi);
  if (PERM) __syncthreads();   // reads hit other threads' write sets
  const float* rc = ryc + d * NQ;
  const float* rs = rys + d * NQ;
  if constexpr (NB == 4) {
    ry_bit<3>(rc[13 - S - 3], rs[13 - S - 3], vr, vi);
    ry_bit<2>(rc[13 - S - 2], rs[13 - S - 2], vr, vi);
  }
  ry_bit<1>(rc[13 - S - 1], rs[13 - S - 1], vr, vi);
  ry_bit<0>(rc[13 - S - 0], rs[13 - S - 0], vr, vi);
  store16<S>(stR, stI, tid, vr, vi);
  __syncthreads();
}

// observable quadratic forms; H (4x4) in LDS, vector on k-bit pairs
__device__ __forceinline__ float obs_q32(const float2* __restrict__ hp,
                                         const float vr[16], const float vi[16]) {
  float2 h[16];
  #pragma unroll
  for (int i = 0; i < 16; ++i) h[i] = hp[i];
  float acc = 0.f;
  #pragma unroll
  for (int o = 0; o < 4; ++o) {
    #pragma unroll
    for (int i = 0; i < 4; ++i) {
      float wr = 0.f, wi = 0.f;
      #pragma unroll
      for (int l = 0; l < 4; ++l) {
        const int kl = (l << 2) | o;
        const float2 hh = h[i * 4 + l];
        wr = fmaf(hh.x, vr[kl], fmaf(-hh.y, vi[kl], wr));
        wi = fmaf(hh.x, vi[kl], fmaf(hh.y, vr[kl], wi));
      }
      const int ki = (i << 2) | o;
      acc = fmaf(vr[ki], wr, fmaf(vi[ki], wi, acc));
    }
  }
  return acc;
}
__device__ __forceinline__ float obs_q21(const float2* __restrict__ hp,
                                         const float vr[16], const float vi[16]) {
  float2 h[16];
  #pragma unroll
  for (int i = 0; i < 16; ++i) h[i] = hp[i];
  float acc = 0.f;
  #pragma unroll
  for (int o = 0; o < 4; ++o) {
    #pragma unroll
    for (int i = 0; i < 4; ++i) {
      float wr = 0.f, wi = 0.f;
      #pragma unroll
      for (int l = 0; l < 4; ++l) {
        const int kl = ((o >> 1) << 3) | (l << 1) | (o & 1);
        const float2 hh = h[i * 4 + l];
        wr = fmaf(hh.x, vr[kl], fmaf(-hh.y, vi[kl], wr));
        wi = fmaf(hh.x, vi[kl], fmaf(hh.y, vr[kl], wi));
      }
      const int ki = ((o >> 1) << 3) | (i << 1) | (o & 1);
      acc = fmaf(vr[ki], wr, fmaf(vi[ki], wi, acc));
    }
  }
  return acc;
}
__device__ __forceinline__ float obs_q10(const float2* __restrict__ hp,
                                         const float vr[16], const float vi[16]) {
  float2 h[16];
  #pragma unroll
  for (int i = 0; i < 16; ++i) h[i] = hp[i];
  float acc = 0.f;
  #pragma unroll
  for (int o = 0; o < 4; ++o) {
    #pragma unroll
    for (int i = 0; i < 4; ++i) {
      float wr = 0.f, wi = 0.f;
      #pragma unroll
      for (int l = 0; l < 4; ++l) {
        const int kl = (o << 2) | l;
        const float2 hh = h[i * 4 + l];
        wr = fmaf(hh.x, vr[kl], fmaf(-hh.y, vi[kl], wr));
        wi = fmaf(hh.x, vi[kl], fmaf(hh.y, vr[kl], wi));
      }
      const int ki = (o << 2) | i;
      acc = fmaf(vr[ki], wr, fmaf(vi[ki], wi, acc));
    }
  }
  return acc;
}

// block=1024 (16 waves/CU, 1 block/CU by LDS). Second arg 4 waves/EU ->
// VGPR cap 128: fits the 16-amp register working set WITHOUT scratch spill.
// (R2 post-mortem: default cap of 64 VGPR spilled vr/vi -> 500 MB HBM traffic.)
__launch_bounds__(TCIRC, 4)
__global__ void circuit_kernel(const float2* __restrict__ Umats,
                               const float* __restrict__ vp,
                               const float* __restrict__ oA,
                               const float* __restrict__ oB,
                               const float* __restrict__ oD,
                               float* __restrict__ out) {
  __shared__ float stR[DIM];                 // 64 KiB
  __shared__ float stI[DIM];                 // 64 KiB
  __shared__ float2 Ush[NGATES * 16];
  __shared__ float2 Hsh[NOBSN * 16];
  __shared__ float  ryc[DEPTHN * NQ];
  __shared__ float  rys[DEPTHN * NQ];
  __shared__ float  red[NOBSN][TCIRC / 64];

  const int b = blockIdx.x;
  const int tid = threadIdx.x;

  for (int i = tid; i < NGATES * 16; i += TCIRC)
    Ush[i] = Umats[b * NGATES * 16 + i];
  for (int i = tid; i < DEPTHN * NQ; i += TCIRC) {
    const float h = 0.5f * vp[i];
    ryc[i] = cosf(h);
    rys[i] = sinf(h);
  }
  if (tid < NOBSN) {
    const int rr[6] = {1, 2, 2, 3, 3, 3};
    const int cc[6] = {0, 0, 1, 0, 1, 2};
    float2 H[16];
    #pragma unroll
    for (int i = 0; i < 16; ++i) H[i] = make_float2(0.f, 0.f);
    for (int m = 0; m < 6; ++m) {
      const float a = oA[tid * 6 + m], bb = oB[tid * 6 + m];
      H[rr[m] * 4 + cc[m]] = make_float2(a, bb);
      H[cc[m] * 4 + rr[m]] = make_float2(a, -bb);
    }
    H[0]  = make_float2(2.f * oD[tid * 4 + 1], 0.f);
    H[5]  = make_float2(2.f * oD[tid * 4 + 2], 0.f);
    H[10] = make_float2(2.f * oD[tid * 4 + 3], 0.f);
    for (int i = 0; i < 16; ++i) Hsh[tid * 16 + i] = H[i];
  }
  for (int y = tid; y < DIM; y += TCIRC) {
    stR[y] = (y == 0) ? 1.f : 0.f;   // E(0)==0
    stI[y] = 0.f;
  }
  __syncthreads();

  // ---- SU(4) brick layer: gate idx g for even q=2m -> m, odd q=2m+1 -> 7+m
  su4_pass<10, 0,  1>(stR, stI, Ush, tid);   // q0 (bits 13,12), q2 (11,10)
  su4_pass< 6, 2,  3>(stR, stI, Ush, tid);   // q4 (9,8),  q6 (7,6)
  su4_pass< 2, 4,  5>(stR, stI, Ush, tid);   // q8 (5,4),  q10 (3,2)
  su4_pass< 0,-1,  6>(stR, stI, Ush, tid);   // q12 (1,0)
  su4_pass< 9, 7,  8>(stR, stI, Ush, tid);   // q1 (12,11), q3 (10,9)
  su4_pass< 5, 9, 10>(stR, stI, Ush, tid);   // q5 (8,7),  q7 (6,5)
  su4_pass< 1,11, 12>(stR, stI, Ush, tid);   // q9 (4,3),  q11 (2,1)

  // ---- variational depths; CNOT chain folded into next pass's reads ----
  ry_pass<10, false, 4>(stR, stI, ryc, rys, tid, 0);
  ry_pass< 6, false, 4>(stR, stI, ryc, rys, tid, 0);
  ry_pass< 2, false, 4>(stR, stI, ryc, rys, tid, 0);
  ry_pass< 0, false, 2>(stR, stI, ryc, rys, tid, 0);
  #pragma unroll 1
  for (int d = 1; d < DEPTHN; ++d) {
    ry_pass<10, true , 4>(stR, stI, ryc, rys, tid, d);  // carries perm of d-1
    ry_pass< 6, false, 4>(stR, stI, ryc, rys, tid, d);
    ry_pass< 2, false, 4>(stR, stI, ryc, rys, tid, d);
    ry_pass< 0, false, 2>(stR, stI, ryc, rys, tid, d);
  }

  // ---- observables: state in LDS is pre-perm of depth 3 -> all reads folded
  float oacc[NOBSN];
  {
    float vr[16], vi[16];
    load16<10, true>(stR, stI, tid, vr, vi);
    oacc[0] = obs_q32(Hsh + 0 * 16, vr, vi);   // bits (13,12)
    oacc[1] = obs_q21(Hsh + 1 * 16, vr, vi);   // (12,11)
    oacc[2] = obs_q10(Hsh + 2 * 16, vr, vi);   // (11,10)
  }
  {
    float vr[16], vi[16];
    load16<7, true>(stR, stI, tid, vr, vi);
    oacc[3] = obs_q32(Hsh + 3 * 16, vr, vi);   // (10,9)
    oacc[4] = obs_q21(Hsh + 4 * 16, vr, vi);   // (9,8)
    oacc[5] = obs_q10(Hsh + 5 * 16, vr, vi);   // (8,7)
  }
  {
    float vr[16], vi[16];
    load16<4, true>(stR, stI, tid, vr, vi);
    oacc[6] = obs_q32(Hsh + 6 * 16, vr, vi);   // (7,6)
    oacc[7] = obs_q21(Hsh + 7 * 16, vr, vi);   // (6,5)
    oacc[8] = obs_q10(Hsh + 8 * 16, vr, vi);   // (5,4)
  }
  {
    float vr[16], vi[16];
    load16<1, true>(stR, stI, tid, vr, vi);
    oacc[9]  = obs_q32(Hsh + 9 * 16, vr, vi);  // (4,3)
    oacc[10] = obs_q21(Hsh + 10 * 16, vr, vi); // (3,2)
    oacc[11] = obs_q10(Hsh + 11 * 16, vr, vi); // (2,1)
  }
  {
    float vr[16], vi[16];
    load16<0, true>(stR, stI, tid, vr, vi);
    oacc[12] = obs_q10(Hsh + 12 * 16, vr, vi); // (1,0)
  }

  const int lane = tid & 63, wid = tid >> 6;
  #pragma unroll
  for (int o = 0; o < NOBSN; ++o) {
    float a = oacc[o];
    #pragma unroll
    for (int off = 32; off > 0; off >>= 1)
      a += __shfl_down(a, off, 64);
    if (lane == 0) red[o][wid] = a;
  }
  __syncthreads();
  if (tid < NOBSN) {
    float s = 0.f;
    #pragma unroll
    for (int w = 0; w < TCIRC / 64; ++w) s += red[tid][w];
    out[b * NOBSN + tid] = s;
  }
}

extern "C" void kernel_launch(void* const* d_in, const int* in_sizes, int n_in,
                              void* d_out, int out_size, void* d_ws, size_t ws_size,
                              hipStream_t stream) {
  const float* x  = (const float*)d_in[0];
  const float* W1 = (const float*)d_in[1];
  const float* b1 = (const float*)d_in[2];
  const float* W2 = (const float*)d_in[3];
  const float* b2 = (const float*)d_in[4];
  const float* vp = (const float*)d_in[5];
  const float* oA = (const float*)d_in[6];
  const float* oB = (const float*)d_in[7];
  const float* oD = (const float*)d_in[8];
  float* out = (float*)d_out;

  float* enc = (float*)d_ws;
  const size_t enc_bytes = (size_t)BATCHN * ENCDIM * sizeof(float);
  float2* U = (float2*)((char*)d_ws + ((enc_bytes + 255) & ~(size_t)255));

  encoder_kernel<<<BATCHN, 256, 0, stream>>>(x, W1, b1, W2, b2, enc);
  build_u_kernel<<<(BATCHN * NGATES + 255) / 256, 256, 0, stream>>>(enc, U);
  circuit_kernel<<<BATCHN, TCIRC, 0, stream>>>(U, vp, oA, oB, oD, out);
}

// Round 4
// 246.076 us; speedup vs baseline: 1.0784x; 1.0380x over previous
//
#include <hip/hip_runtime.h>
#include <math.h>

#define NQ        14
#define DIM       16384      // 2^14
#define BATCHN    128
#define NGATES    13
#define NGEN      15
#define NOBSN     13
#define DEPTHN    4
#define INDIM     256
#define HIDDIM    256
#define ENCDIM    195
#define TCIRC     1024

// Pauli 2x2 matrices (real, imag parts). Order: I, X, Y, Z.
__constant__ float c_PR[4][2][2] = {
  {{1.f, 0.f}, {0.f, 1.f}},   // I
  {{0.f, 1.f}, {1.f, 0.f}},   // X
  {{0.f, 0.f}, {0.f, 0.f}},   // Y (real part)
  {{1.f, 0.f}, {0.f,-1.f}},   // Z
};
__constant__ float c_PI[4][2][2] = {
  {{0.f, 0.f}, {0.f, 0.f}},
  {{0.f, 0.f}, {0.f, 0.f}},
  {{0.f,-1.f}, {1.f, 0.f}},   // Y (imag part)
  {{0.f, 0.f}, {0.f, 0.f}},
};

// ---------------- encoder: enc = silu(x W1^T + b1) W2^T + b2 ----------------
__global__ void encoder_kernel(const float* __restrict__ x,
                               const float* __restrict__ W1,
                               const float* __restrict__ b1,
                               const float* __restrict__ W2,
                               const float* __restrict__ b2,
                               float* __restrict__ enc) {
  __shared__ float xrow[INDIM];
  __shared__ float hrow[HIDDIM];
  const int b = blockIdx.x, t = threadIdx.x;
  xrow[t] = x[b * INDIM + t];
  __syncthreads();
  float acc = b1[t];
  const float* w = W1 + t * INDIM;
  for (int k = 0; k < INDIM; ++k) acc = fmaf(w[k], xrow[k], acc);
  hrow[t] = acc / (1.f + expf(-acc));       // silu
  __syncthreads();
  if (t < ENCDIM) {
    float a2 = b2[t];
    const float* w2 = W2 + t * HIDDIM;
    for (int k = 0; k < HIDDIM; ++k) a2 = fmaf(w2[k], hrow[k], a2);
    enc[b * ENCDIM + t] = a2;
  }
}

// ---------------- build U = exp(i * sum_g theta_g G_g), one thread each -----
__global__ void build_u_kernel(const float* __restrict__ enc,
                               float2* __restrict__ Umats) {
  const int idx = blockIdx.x * blockDim.x + threadIdx.x;
  if (idx >= BATCHN * NGATES) return;
  const int b = idx / NGATES, g = idx % NGATES;
  const float* th = enc + b * ENCDIM + g * NGEN;

  float Ar[16], Ai[16];
  for (int i = 0; i < 16; ++i) { Ar[i] = 0.f; Ai[i] = 0.f; }
  for (int t = 0; t < NGEN; ++t) {
    const int p = t + 1;
    const int pa = p >> 2, pb = p & 3;
    const float theta = th[t];
    for (int i = 0; i < 4; ++i)
      for (int j = 0; j < 4; ++j) {
        const float ar = c_PR[pa][i >> 1][j >> 1], ai = c_PI[pa][i >> 1][j >> 1];
        const float br = c_PR[pb][i & 1][j & 1],  bi = c_PI[pb][i & 1][j & 1];
        Ar[i * 4 + j] = fmaf(theta, ar * br - ai * bi, Ar[i * 4 + j]);
        Ai[i * 4 + j] = fmaf(theta, ar * bi + ai * br, Ai[i * 4 + j]);
      }
  }

  float nrm = 0.f;
  for (int i = 0; i < 4; ++i) {
    float rs = 0.f;
    for (int j = 0; j < 4; ++j)
      rs += sqrtf(Ar[i * 4 + j] * Ar[i * 4 + j] + Ai[i * 4 + j] * Ai[i * 4 + j]);
    nrm = fmaxf(nrm, rs);
  }
  int sct = 0;
  float scale = 1.f;
  while (nrm * scale > 0.4f && sct < 30) { scale *= 0.5f; ++sct; }

  float Mr[16], Mi[16];
  for (int i = 0; i < 16; ++i) { Mr[i] = -Ai[i] * scale; Mi[i] = Ar[i] * scale; }

  float Rr[16], Ri[16];
  for (int i = 0; i < 16; ++i) { Rr[i] = (i % 5 == 0) ? 1.f : 0.f; Ri[i] = 0.f; }
  for (int k = 12; k >= 1; --k) {
    float Tr[16], Ti[16];
    const float inv = 1.f / (float)k;
    for (int i = 0; i < 4; ++i)
      for (int j = 0; j < 4; ++j) {
        float tr = 0.f, ti = 0.f;
        for (int l = 0; l < 4; ++l) {
          const float mr = Mr[i * 4 + l], mi = Mi[i * 4 + l];
          const float rr = Rr[l * 4 + j], ri = Ri[l * 4 + j];
          tr += mr * rr - mi * ri;
          ti += mr * ri + mi * rr;
        }
        Tr[i * 4 + j] = ((i == j) ? 1.f : 0.f) + inv * tr;
        Ti[i * 4 + j] = inv * ti;
      }
    for (int i = 0; i < 16; ++i) { Rr[i] = Tr[i]; Ri[i] = Ti[i]; }
  }
  for (int it = 0; it < sct; ++it) {
    float Tr[16], Ti[16];
    for (int i = 0; i < 4; ++i)
      for (int j = 0; j < 4; ++j) {
        float tr = 0.f, ti = 0.f;
        for (int l = 0; l < 4; ++l) {
          const float ar = Rr[i * 4 + l], ai = Ri[i * 4 + l];
          const float br = Rr[l * 4 + j], bi = Ri[l * 4 + j];
          tr += ar * br - ai * bi;
          ti += ar * bi + ai * br;
        }
        Tr[i * 4 + j] = tr; Ti[i * 4 + j] = ti;
      }
    for (int i = 0; i < 16; ++i) { Rr[i] = Tr[i]; Ri[i] = Ti[i]; }
  }
  for (int i = 0; i < 16; ++i)
    Umats[idx * 16 + i] = make_float2(Rr[i], Ri[i]);
}

// ================= circuit kernel: 16 amps/thread, SoA + XOR swizzle ========
// Amplitude y lives at element index E(y); E is GF(2)-linear so
// E(a|b) = E(a)^E(b) for disjoint-bit a,b. Chosen so that every pass quad
// used below is bank-conflict-free (2 lanes/bank).
__device__ __forceinline__ int Efun(int y) {
  return y ^ (((y >> 5) ^ (y >> 10)) & 31);
}
// Composed CNOT-chain permutation: bit b ^= bit b+1.
__device__ __forceinline__ int sigf(int y) { return y ^ ((y >> 1) & 8191); }

// gate on k-bits (3,2): vector index = k>>2, groups r = k&3
__device__ __forceinline__ void gate_hi(const float2* __restrict__ ug,
                                        float vr[16], float vi[16]) {
  float2 u[16];
  #pragma unroll
  for (int i = 0; i < 16; ++i) u[i] = ug[i];
  #pragma unroll
  for (int r = 0; r < 4; ++r) {
    float ar[4], ai[4];
    #pragma unroll
    for (int i = 0; i < 4; ++i) {
      float sr = 0.f, si = 0.f;
      #pragma unroll
      for (int l = 0; l < 4; ++l) {
        const float2 uu = u[i * 4 + l];
        const float xr = vr[(l << 2) | r], xi = vi[(l << 2) | r];
        sr = fmaf(uu.x, xr, fmaf(-uu.y, xi, sr));
        si = fmaf(uu.x, xi, fmaf(uu.y, xr, si));
      }
      ar[i] = sr; ai[i] = si;
    }
    #pragma unroll
    for (int i = 0; i < 4; ++i) { vr[(i << 2) | r] = ar[i]; vi[(i << 2) | r] = ai[i]; }
  }
}

// gate on k-bits (1,0): vector index = k&3, groups r = k>>2
__device__ __forceinline__ void gate_lo(const float2* __restrict__ ug,
                                        float vr[16], float vi[16]) {
  float2 u[16];
  #pragma unroll
  for (int i = 0; i < 16; ++i) u[i] = ug[i];
  #pragma unroll
  for (int r = 0; r < 4; ++r) {
    float ar[4], ai[4];
    #pragma unroll
    for (int i = 0; i < 4; ++i) {
      float sr = 0.f, si = 0.f;
      #pragma unroll
      for (int l = 0; l < 4; ++l) {
        const float2 uu = u[i * 4 + l];
        const float xr = vr[(r << 2) | l], xi = vi[(r << 2) | l];
        sr = fmaf(uu.x, xr, fmaf(-uu.y, xi, sr));
        si = fmaf(uu.x, xi, fmaf(uu.y, xr, si));
      }
      ar[i] = sr; ai[i] = si;
    }
    #pragma unroll
    for (int i = 0; i < 4; ++i) { vr[(r << 2) | i] = ar[i]; vi[(r << 2) | i] = ai[i]; }
  }
}

template<int J>
__device__ __forceinline__ void ry_bit(float c, float s, float vr[16], float vi[16]) {
  #pragma unroll
  for (int k = 0; k < 16; ++k) {
    if ((k & (1 << J)) == 0) {
      const int k1 = k | (1 << J);
      const float ar = vr[k], ai = vi[k], br = vr[k1], bi = vi[k1];
      vr[k]  = fmaf(c, ar, -(s * br));
      vi[k]  = fmaf(c, ai, -(s * bi));
      vr[k1] = fmaf(s, ar, c * br);
      vi[k1] = fmaf(s, ai, c * bi);
    }
  }
}

template<int S, bool PERM>
__device__ __forceinline__ void load16(const float* __restrict__ stR,
                                       const float* __restrict__ stI,
                                       int tid, float vr[16], float vi[16]) {
  const int m = (1 << S) - 1;
  const int B = ((tid & ~m) << 4) | (tid & m);
  #pragma unroll
  for (int k = 0; k < 16; ++k) {
    const int y = B | (k << S);
    const int a = Efun(PERM ? sigf(y) : y);
    vr[k] = stR[a]; vi[k] = stI[a];
  }
}

template<int S>
__device__ __forceinline__ void store16(float* __restrict__ stR, float* __restrict__ stI,
                                        int tid, const float vr[16], const float vi[16]) {
  const int m = (1 << S) - 1;
  const int B = ((tid & ~m) << 4) | (tid & m);
  #pragma unroll
  for (int k = 0; k < 16; ++k) {
    const int a = Efun(B | (k << S));
    stR[a] = vr[k]; stI[a] = vi[k];
  }
}

template<int S, int GHI, int GLO>
__device__ __forceinline__ void su4_pass(float* stR, float* stI,
                                         const float2* __restrict__ Ush, int tid) {
  float vr[16], vi[16];
  load16<S, false>(stR, stI, tid, vr, vi);
  if (GHI >= 0) gate_hi(Ush + GHI * 16, vr, vi);
  if (GLO >= 0) gate_lo(Ush + GLO * 16, vr, vi);
  store16<S>(stR, stI, tid, vr, vi);
  __syncthreads();
}

template<int S, bool PERM, int NB>
__device__ __forceinline__ void ry_pass(float* stR, float* stI,
                                        const float* __restrict__ ryc,
                                        const float* __restrict__ rys,
                                        int tid, int d) {
  float vr[16], vi[16];
  load16<S, PERM>(stR, stI, tid, vr, vi);
  if (PERM) __syncthreads();   // reads hit other threads' write sets
  const float* rc = ryc + d * NQ;
  const float* rs = rys + d * NQ;
  if constexpr (NB == 4) {
    ry_bit<3>(rc[13 - S - 3], rs[13 - S - 3], vr, vi);
    ry_bit<2>(rc[13 - S - 2], rs[13 - S - 2], vr, vi);
  }
  ry_bit<1>(rc[13 - S - 1], rs[13 - S - 1], vr, vi);
  ry_bit<0>(rc[13 - S - 0], rs[13 - S - 0], vr, vi);
  store16<S>(stR, stI, tid, vr, vi);
  __syncthreads();
}

// observable quadratic forms; H (4x4) in LDS, vector on k-bit pairs
__device__ __forceinline__ float obs_q32(const float2* __restrict__ hp,
                                         const float vr[16], const float vi[16]) {
  float2 h[16];
  #pragma unroll
  for (int i = 0; i < 16; ++i) h[i] = hp[i];
  float acc = 0.f;
  #pragma unroll
  for (int o = 0; o < 4; ++o) {
    #pragma unroll
    for (int i = 0; i < 4; ++i) {
      float wr = 0.f, wi = 0.f;
      #pragma unroll
      for (int l = 0; l < 4; ++l) {
        const int kl = (l << 2) | o;
        const float2 hh = h[i * 4 + l];
        wr = fmaf(hh.x, vr[kl], fmaf(-hh.y, vi[kl], wr));
        wi = fmaf(hh.x, vi[kl], fmaf(hh.y, vr[kl], wi));
      }
      const int ki = (i << 2) | o;
      acc = fmaf(vr[ki], wr, fmaf(vi[ki], wi, acc));
    }
  }
  return acc;
}
__device__ __forceinline__ float obs_q21(const float2* __restrict__ hp,
                                         const float vr[16], const float vi[16]) {
  float2 h[16];
  #pragma unroll
  for (int i = 0; i < 16; ++i) h[i] = hp[i];
  float acc = 0.f;
  #pragma unroll
  for (int o = 0; o < 4; ++o) {
    #pragma unroll
    for (int i = 0; i < 4; ++i) {
      float wr = 0.f, wi = 0.f;
      #pragma unroll
      for (int l = 0; l < 4; ++l) {
        const int kl = ((o >> 1) << 3) | (l << 1) | (o & 1);
        const float2 hh = h[i * 4 + l];
        wr = fmaf(hh.x, vr[kl], fmaf(-hh.y, vi[kl], wr));
        wi = fmaf(hh.x, vi[kl], fmaf(hh.y, vr[kl], wi));
      }
      const int ki = ((o >> 1) << 3) | (i << 1) | (o & 1);
      acc = fmaf(vr[ki], wr, fmaf(vi[ki], wi, acc));
    }
  }
  return acc;
}
__device__ __forceinline__ float obs_q10(const float2* __restrict__ hp,
                                         const float vr[16], const float vi[16]) {
  float2 h[16];
  #pragma unroll
  for (int i = 0; i < 16; ++i) h[i] = hp[i];
  float acc = 0.f;
  #pragma unroll
  for (int o = 0; o < 4; ++o) {
    #pragma unroll
    for (int i = 0; i < 4; ++i) {
      float wr = 0.f, wi = 0.f;
      #pragma unroll
      for (int l = 0; l < 4; ++l) {
        const int kl = (o << 2) | l;
        const float2 hh = h[i * 4 + l];
        wr = fmaf(hh.x, vr[kl], fmaf(-hh.y, vi[kl], wr));
        wi = fmaf(hh.x, vi[kl], fmaf(hh.y, vr[kl], wi));
      }
      const int ki = (o << 2) | i;
      acc = fmaf(vr[ki], wr, fmaf(vi[ki], wi, acc));
    }
  }
  return acc;
}

// R3 post-mortem: __launch_bounds__(1024,4) sets only the waves-per-eu MIN;
// the allocator still targeted 8 waves/EU -> 64-VGPR cap -> spilled vr/vi to
// scratch (500 MB HBM). LDS (132KB) already limits us to 1 block/CU = 4
// waves/EU, so force the allocator's occupancy target to exactly [4,4] ->
// 128-VGPR budget, no spill, occupancy unchanged.
__attribute__((amdgpu_waves_per_eu(4, 4)))
__global__ void __launch_bounds__(TCIRC)
circuit_kernel(const float2* __restrict__ Umats,
               const float* __restrict__ vp,
               const float* __restrict__ oA,
               const float* __restrict__ oB,
               const float* __restrict__ oD,
               float* __restrict__ out) {
  __shared__ float stR[DIM];                 // 64 KiB
  __shared__ float stI[DIM];                 // 64 KiB
  __shared__ float2 Ush[NGATES * 16];
  __shared__ float2 Hsh[NOBSN * 16];
  __shared__ float  ryc[DEPTHN * NQ];
  __shared__ float  rys[DEPTHN * NQ];
  __shared__ float  red[NOBSN][TCIRC / 64];

  const int b = blockIdx.x;
  const int tid = threadIdx.x;

  for (int i = tid; i < NGATES * 16; i += TCIRC)
    Ush[i] = Umats[b * NGATES * 16 + i];
  for (int i = tid; i < DEPTHN * NQ; i += TCIRC) {
    const float h = 0.5f * vp[i];
    ryc[i] = cosf(h);
    rys[i] = sinf(h);
  }
  if (tid < NOBSN) {
    const int rr[6] = {1, 2, 2, 3, 3, 3};
    const int cc[6] = {0, 0, 1, 0, 1, 2};
    float2 H[16];
    #pragma unroll
    for (int i = 0; i < 16; ++i) H[i] = make_float2(0.f, 0.f);
    for (int m = 0; m < 6; ++m) {
      const float a = oA[tid * 6 + m], bb = oB[tid * 6 + m];
      H[rr[m] * 4 + cc[m]] = make_float2(a, bb);
      H[cc[m] * 4 + rr[m]] = make_float2(a, -bb);
    }
    H[0]  = make_float2(2.f * oD[tid * 4 + 1], 0.f);
    H[5]  = make_float2(2.f * oD[tid * 4 + 2], 0.f);
    H[10] = make_float2(2.f * oD[tid * 4 + 3], 0.f);
    for (int i = 0; i < 16; ++i) Hsh[tid * 16 + i] = H[i];
  }
  for (int y = tid; y < DIM; y += TCIRC) {
    stR[y] = (y == 0) ? 1.f : 0.f;   // E(0)==0
    stI[y] = 0.f;
  }
  __syncthreads();

  // ---- SU(4) brick layer: gate idx g for even q=2m -> m, odd q=2m+1 -> 7+m
  su4_pass<10, 0,  1>(stR, stI, Ush, tid);   // q0 (bits 13,12), q2 (11,10)
  su4_pass< 6, 2,  3>(stR, stI, Ush, tid);   // q4 (9,8),  q6 (7,6)
  su4_pass< 2, 4,  5>(stR, stI, Ush, tid);   // q8 (5,4),  q10 (3,2)
  su4_pass< 0,-1,  6>(stR, stI, Ush, tid);   // q12 (1,0)
  su4_pass< 9, 7,  8>(stR, stI, Ush, tid);   // q1 (12,11), q3 (10,9)
  su4_pass< 5, 9, 10>(stR, stI, Ush, tid);   // q5 (8,7),  q7 (6,5)
  su4_pass< 1,11, 12>(stR, stI, Ush, tid);   // q9 (4,3),  q11 (2,1)

  // ---- variational depths; CNOT chain folded into next pass's reads ----
  ry_pass<10, false, 4>(stR, stI, ryc, rys, tid, 0);
  ry_pass< 6, false, 4>(stR, stI, ryc, rys, tid, 0);
  ry_pass< 2, false, 4>(stR, stI, ryc, rys, tid, 0);
  ry_pass< 0, false, 2>(stR, stI, ryc, rys, tid, 0);
  #pragma unroll 1
  for (int d = 1; d < DEPTHN; ++d) {
    ry_pass<10, true , 4>(stR, stI, ryc, rys, tid, d);  // carries perm of d-1
    ry_pass< 6, false, 4>(stR, stI, ryc, rys, tid, d);
    ry_pass< 2, false, 4>(stR, stI, ryc, rys, tid, d);
    ry_pass< 0, false, 2>(stR, stI, ryc, rys, tid, d);
  }

  // ---- observables: state in LDS is pre-perm of depth 3 -> all reads folded
  float oacc[NOBSN];
  {
    float vr[16], vi[16];
    load16<10, true>(stR, stI, tid, vr, vi);
    oacc[0] = obs_q32(Hsh + 0 * 16, vr, vi);   // bits (13,12)
    oacc[1] = obs_q21(Hsh + 1 * 16, vr, vi);   // (12,11)
    oacc[2] = obs_q10(Hsh + 2 * 16, vr, vi);   // (11,10)
  }
  {
    float vr[16], vi[16];
    load16<7, true>(stR, stI, tid, vr, vi);
    oacc[3] = obs_q32(Hsh + 3 * 16, vr, vi);   // (10,9)
    oacc[4] = obs_q21(Hsh + 4 * 16, vr, vi);   // (9,8)
    oacc[5] = obs_q10(Hsh + 5 * 16, vr, vi);   // (8,7)
  }
  {
    float vr[16], vi[16];
    load16<4, true>(stR, stI, tid, vr, vi);
    oacc[6] = obs_q32(Hsh + 6 * 16, vr, vi);   // (7,6)
    oacc[7] = obs_q21(Hsh + 7 * 16, vr, vi);   // (6,5)
    oacc[8] = obs_q10(Hsh + 8 * 16, vr, vi);   // (5,4)
  }
  {
    float vr[16], vi[16];
    load16<1, true>(stR, stI, tid, vr, vi);
    oacc[9]  = obs_q32(Hsh + 9 * 16, vr, vi);  // (4,3)
    oacc[10] = obs_q21(Hsh + 10 * 16, vr, vi); // (3,2)
    oacc[11] = obs_q10(Hsh + 11 * 16, vr, vi); // (2,1)
  }
  {
    float vr[16], vi[16];
    load16<0, true>(stR, stI, tid, vr, vi);
    oacc[12] = obs_q10(Hsh + 12 * 16, vr, vi); // (1,0)
  }

  const int lane = tid & 63, wid = tid >> 6;
  #pragma unroll
  for (int o = 0; o < NOBSN; ++o) {
    float a = oacc[o];
    #pragma unroll
    for (int off = 32; off > 0; off >>= 1)
      a += __shfl_down(a, off, 64);
    if (lane == 0) red[o][wid] = a;
  }
  __syncthreads();
  if (tid < NOBSN) {
    float s = 0.f;
    #pragma unroll
    for (int w = 0; w < TCIRC / 64; ++w) s += red[tid][w];
    out[b * NOBSN + tid] = s;
  }
}

extern "C" void kernel_launch(void* const* d_in, const int* in_sizes, int n_in,
                              void* d_out, int out_size, void* d_ws, size_t ws_size,
                              hipStream_t stream) {
  const float* x  = (const float*)d_in[0];
  const float* W1 = (const float*)d_in[1];
  const float* b1 = (const float*)d_in[2];
  const float* W2 = (const float*)d_in[3];
  const float* b2 = (const float*)d_in[4];
  const float* vp = (const float*)d_in[5];
  const float* oA = (const float*)d_in[6];
  const float* oB = (const float*)d_in[7];
  const float* oD = (const float*)d_in[8];
  float* out = (float*)d_out;

  float* enc = (float*)d_ws;
  const size_t enc_bytes = (size_t)BATCHN * ENCDIM * sizeof(float);
  float2* U = (float2*)((char*)d_ws + ((enc_bytes + 255) & ~(size_t)255));

  encoder_kernel<<<BATCHN, 256, 0, stream>>>(x, W1, b1, W2, b2, enc);
  build_u_kernel<<<(BATCHN * NGATES + 255) / 256, 256, 0, stream>>>(enc, U);
  circuit_kernel<<<BATCHN, TCIRC, 0, stream>>>(U, vp, oA, oB, oD, out);
}

// Round 5
// 192.171 us; speedup vs baseline: 1.3808x; 1.2805x over previous
//
#include <hip/hip_runtime.h>
#include <math.h>

#define NQ        14
#define DIM       16384      // 2^14
#define BATCHN    128
#define NGATES    13
#define NGEN      15
#define NOBSN     13
#define DEPTHN    4
#define INDIM     256
#define HIDDIM    256
#define ENCDIM    195
#define TCIRC     1024

// Pauli 2x2 matrices (real, imag parts). Order: I, X, Y, Z.
__constant__ float c_PR[4][2][2] = {
  {{1.f, 0.f}, {0.f, 1.f}},   // I
  {{0.f, 1.f}, {1.f, 0.f}},   // X
  {{0.f, 0.f}, {0.f, 0.f}},   // Y (real part)
  {{1.f, 0.f}, {0.f,-1.f}},   // Z
};
__constant__ float c_PI[4][2][2] = {
  {{0.f, 0.f}, {0.f, 0.f}},
  {{0.f, 0.f}, {0.f, 0.f}},
  {{0.f,-1.f}, {1.f, 0.f}},   // Y (imag part)
  {{0.f, 0.f}, {0.f, 0.f}},
};

// ---------------- encoder: enc = silu(x W1^T + b1) W2^T + b2 ----------------
__global__ void encoder_kernel(const float* __restrict__ x,
                               const float* __restrict__ W1,
                               const float* __restrict__ b1,
                               const float* __restrict__ W2,
                               const float* __restrict__ b2,
                               float* __restrict__ enc) {
  __shared__ float xrow[INDIM];
  __shared__ float hrow[HIDDIM];
  const int b = blockIdx.x, t = threadIdx.x;
  xrow[t] = x[b * INDIM + t];
  __syncthreads();
  float acc = b1[t];
  const float* w = W1 + t * INDIM;
  for (int k = 0; k < INDIM; ++k) acc = fmaf(w[k], xrow[k], acc);
  hrow[t] = acc / (1.f + expf(-acc));       // silu
  __syncthreads();
  if (t < ENCDIM) {
    float a2 = b2[t];
    const float* w2 = W2 + t * HIDDIM;
    for (int k = 0; k < HIDDIM; ++k) a2 = fmaf(w2[k], hrow[k], a2);
    enc[b * ENCDIM + t] = a2;
  }
}

// ---------------- build U = exp(i * sum_g theta_g G_g), one thread each -----
__global__ void build_u_kernel(const float* __restrict__ enc,
                               float2* __restrict__ Umats) {
  const int idx = blockIdx.x * blockDim.x + threadIdx.x;
  if (idx >= BATCHN * NGATES) return;
  const int b = idx / NGATES, g = idx % NGATES;
  const float* th = enc + b * ENCDIM + g * NGEN;

  float Ar[16], Ai[16];
  for (int i = 0; i < 16; ++i) { Ar[i] = 0.f; Ai[i] = 0.f; }
  for (int t = 0; t < NGEN; ++t) {
    const int p = t + 1;
    const int pa = p >> 2, pb = p & 3;
    const float theta = th[t];
    for (int i = 0; i < 4; ++i)
      for (int j = 0; j < 4; ++j) {
        const float ar = c_PR[pa][i >> 1][j >> 1], ai = c_PI[pa][i >> 1][j >> 1];
        const float br = c_PR[pb][i & 1][j & 1],  bi = c_PI[pb][i & 1][j & 1];
        Ar[i * 4 + j] = fmaf(theta, ar * br - ai * bi, Ar[i * 4 + j]);
        Ai[i * 4 + j] = fmaf(theta, ar * bi + ai * br, Ai[i * 4 + j]);
      }
  }

  float nrm = 0.f;
  for (int i = 0; i < 4; ++i) {
    float rs = 0.f;
    for (int j = 0; j < 4; ++j)
      rs += sqrtf(Ar[i * 4 + j] * Ar[i * 4 + j] + Ai[i * 4 + j] * Ai[i * 4 + j]);
    nrm = fmaxf(nrm, rs);
  }
  int sct = 0;
  float scale = 1.f;
  while (nrm * scale > 0.4f && sct < 30) { scale *= 0.5f; ++sct; }

  float Mr[16], Mi[16];
  for (int i = 0; i < 16; ++i) { Mr[i] = -Ai[i] * scale; Mi[i] = Ar[i] * scale; }

  float Rr[16], Ri[16];
  for (int i = 0; i < 16; ++i) { Rr[i] = (i % 5 == 0) ? 1.f : 0.f; Ri[i] = 0.f; }
  for (int k = 12; k >= 1; --k) {
    float Tr[16], Ti[16];
    const float inv = 1.f / (float)k;
    for (int i = 0; i < 4; ++i)
      for (int j = 0; j < 4; ++j) {
        float tr = 0.f, ti = 0.f;
        for (int l = 0; l < 4; ++l) {
          const float mr = Mr[i * 4 + l], mi = Mi[i * 4 + l];
          const float rr = Rr[l * 4 + j], ri = Ri[l * 4 + j];
          tr += mr * rr - mi * ri;
          ti += mr * ri + mi * rr;
        }
        Tr[i * 4 + j] = ((i == j) ? 1.f : 0.f) + inv * tr;
        Ti[i * 4 + j] = inv * ti;
      }
    for (int i = 0; i < 16; ++i) { Rr[i] = Tr[i]; Ri[i] = Ti[i]; }
  }
  for (int it = 0; it < sct; ++it) {
    float Tr[16], Ti[16];
    for (int i = 0; i < 4; ++i)
      for (int j = 0; j < 4; ++j) {
        float tr = 0.f, ti = 0.f;
        for (int l = 0; l < 4; ++l) {
          const float ar = Rr[i * 4 + l], ai = Ri[i * 4 + l];
          const float br = Rr[l * 4 + j], bi = Ri[l * 4 + j];
          tr += ar * br - ai * bi;
          ti += ar * bi + ai * br;
        }
        Tr[i * 4 + j] = tr; Ti[i * 4 + j] = ti;
      }
    for (int i = 0; i < 16; ++i) { Rr[i] = Tr[i]; Ri[i] = Ti[i]; }
  }
  for (int i = 0; i < 16; ++i)
    Umats[idx * 16 + i] = make_float2(Rr[i], Ri[i]);
}

// ================= circuit kernel: 16 amps/thread, SoA + XOR swizzle ========
// R4 post-mortem: neither __launch_bounds__(,4) nor amdgpu_waves_per_eu(4,4)
// raised the 64-VGPR cap; the cached u[16]/h[16] matrices (32 VGPRs) pushed
// the live set to ~100 -> scratch spill (500 MB HBM). Fix: the matrices are
// WAVE-UNIFORM -> force them into SGPRs via readfirstlane. VGPR live set
// drops to ~48 (32 amps + 8 accums + addr) and fits the 64-reg budget.
__device__ __forceinline__ float rfl(float x) {
  return __int_as_float(__builtin_amdgcn_readfirstlane(__float_as_int(x)));
}

// Amplitude y lives at element index E(y); E is GF(2)-linear so
// E(a|b) = E(a)^E(b) for disjoint-bit a,b. Chosen so that every pass quad
// used below is bank-conflict-free (2 lanes/bank).
__device__ __forceinline__ int Efun(int y) {
  return y ^ (((y >> 5) ^ (y >> 10)) & 31);
}
// Composed CNOT-chain permutation: bit b ^= bit b+1.
__device__ __forceinline__ int sigf(int y) { return y ^ ((y >> 1) & 8191); }

// gate on k-bits (3,2): vector index = k>>2, groups r = k&3
__device__ __forceinline__ void gate_hi(const float2* __restrict__ ug,
                                        float vr[16], float vi[16]) {
  float ur[16], uix[16];
  #pragma unroll
  for (int i = 0; i < 16; ++i) { ur[i] = rfl(ug[i].x); uix[i] = rfl(ug[i].y); }
  #pragma unroll
  for (int r = 0; r < 4; ++r) {
    float ar[4], ai[4];
    #pragma unroll
    for (int i = 0; i < 4; ++i) {
      float sr = 0.f, si = 0.f;
      #pragma unroll
      for (int l = 0; l < 4; ++l) {
        const float xr = vr[(l << 2) | r], xi = vi[(l << 2) | r];
        sr = fmaf(ur[i * 4 + l], xr, fmaf(-uix[i * 4 + l], xi, sr));
        si = fmaf(ur[i * 4 + l], xi, fmaf(uix[i * 4 + l], xr, si));
      }
      ar[i] = sr; ai[i] = si;
    }
    #pragma unroll
    for (int i = 0; i < 4; ++i) { vr[(i << 2) | r] = ar[i]; vi[(i << 2) | r] = ai[i]; }
  }
}

// gate on k-bits (1,0): vector index = k&3, groups r = k>>2
__device__ __forceinline__ void gate_lo(const float2* __restrict__ ug,
                                        float vr[16], float vi[16]) {
  float ur[16], uix[16];
  #pragma unroll
  for (int i = 0; i < 16; ++i) { ur[i] = rfl(ug[i].x); uix[i] = rfl(ug[i].y); }
  #pragma unroll
  for (int r = 0; r < 4; ++r) {
    float ar[4], ai[4];
    #pragma unroll
    for (int i = 0; i < 4; ++i) {
      float sr = 0.f, si = 0.f;
      #pragma unroll
      for (int l = 0; l < 4; ++l) {
        const float xr = vr[(r << 2) | l], xi = vi[(r << 2) | l];
        sr = fmaf(ur[i * 4 + l], xr, fmaf(-uix[i * 4 + l], xi, sr));
        si = fmaf(ur[i * 4 + l], xi, fmaf(uix[i * 4 + l], xr, si));
      }
      ar[i] = sr; ai[i] = si;
    }
    #pragma unroll
    for (int i = 0; i < 4; ++i) { vr[(r << 2) | i] = ar[i]; vi[(r << 2) | i] = ai[i]; }
  }
}

template<int J>
__device__ __forceinline__ void ry_bit(float c, float s, float vr[16], float vi[16]) {
  #pragma unroll
  for (int k = 0; k < 16; ++k) {
    if ((k & (1 << J)) == 0) {
      const int k1 = k | (1 << J);
      const float ar = vr[k], ai = vi[k], br = vr[k1], bi = vi[k1];
      vr[k]  = fmaf(c, ar, -(s * br));
      vi[k]  = fmaf(c, ai, -(s * bi));
      vr[k1] = fmaf(s, ar, c * br);
      vi[k1] = fmaf(s, ai, c * bi);
    }
  }
}

template<int S, bool PERM>
__device__ __forceinline__ void load16(const float* __restrict__ stR,
                                       const float* __restrict__ stI,
                                       int tid, float vr[16], float vi[16]) {
  const int m = (1 << S) - 1;
  const int B = ((tid & ~m) << 4) | (tid & m);
  #pragma unroll
  for (int k = 0; k < 16; ++k) {
    const int y = B | (k << S);
    const int a = Efun(PERM ? sigf(y) : y);
    vr[k] = stR[a]; vi[k] = stI[a];
  }
}

template<int S>
__device__ __forceinline__ void store16(float* __restrict__ stR, float* __restrict__ stI,
                                        int tid, const float vr[16], const float vi[16]) {
  const int m = (1 << S) - 1;
  const int B = ((tid & ~m) << 4) | (tid & m);
  #pragma unroll
  for (int k = 0; k < 16; ++k) {
    const int a = Efun(B | (k << S));
    stR[a] = vr[k]; stI[a] = vi[k];
  }
}

template<int S, int GHI, int GLO>
__device__ __forceinline__ void su4_pass(float* stR, float* stI,
                                         const float2* __restrict__ Ush, int tid) {
  float vr[16], vi[16];
  load16<S, false>(stR, stI, tid, vr, vi);
  if (GHI >= 0) gate_hi(Ush + GHI * 16, vr, vi);
  if (GLO >= 0) gate_lo(Ush + GLO * 16, vr, vi);
  store16<S>(stR, stI, tid, vr, vi);
  __syncthreads();
}

template<int S, bool PERM, int NB>
__device__ __forceinline__ void ry_pass(float* stR, float* stI,
                                        const float* __restrict__ ryc,
                                        const float* __restrict__ rys,
                                        int tid, int d) {
  float vr[16], vi[16];
  load16<S, PERM>(stR, stI, tid, vr, vi);
  if (PERM) __syncthreads();   // reads hit other threads' write sets
  const float* rc = ryc + d * NQ;
  const float* rs = rys + d * NQ;
  if constexpr (NB == 4) {
    ry_bit<3>(rfl(rc[13 - S - 3]), rfl(rs[13 - S - 3]), vr, vi);
    ry_bit<2>(rfl(rc[13 - S - 2]), rfl(rs[13 - S - 2]), vr, vi);
  }
  ry_bit<1>(rfl(rc[13 - S - 1]), rfl(rs[13 - S - 1]), vr, vi);
  ry_bit<0>(rfl(rc[13 - S - 0]), rfl(rs[13 - S - 0]), vr, vi);
  store16<S>(stR, stI, tid, vr, vi);
  __syncthreads();
}

// observable quadratic forms; H (4x4, wave-uniform -> SGPR) on k-bit pairs
__device__ __forceinline__ float obs_q32(const float2* __restrict__ hp,
                                         const float vr[16], const float vi[16]) {
  float hr[16], hi[16];
  #pragma unroll
  for (int i = 0; i < 16; ++i) { hr[i] = rfl(hp[i].x); hi[i] = rfl(hp[i].y); }
  float acc = 0.f;
  #pragma unroll
  for (int o = 0; o < 4; ++o) {
    #pragma unroll
    for (int i = 0; i < 4; ++i) {
      float wr = 0.f, wi = 0.f;
      #pragma unroll
      for (int l = 0; l < 4; ++l) {
        const int kl = (l << 2) | o;
        wr = fmaf(hr[i * 4 + l], vr[kl], fmaf(-hi[i * 4 + l], vi[kl], wr));
        wi = fmaf(hr[i * 4 + l], vi[kl], fmaf(hi[i * 4 + l], vr[kl], wi));
      }
      const int ki = (i << 2) | o;
      acc = fmaf(vr[ki], wr, fmaf(vi[ki], wi, acc));
    }
  }
  return acc;
}
__device__ __forceinline__ float obs_q21(const float2* __restrict__ hp,
                                         const float vr[16], const float vi[16]) {
  float hr[16], hi[16];
  #pragma unroll
  for (int i = 0; i < 16; ++i) { hr[i] = rfl(hp[i].x); hi[i] = rfl(hp[i].y); }
  float acc = 0.f;
  #pragma unroll
  for (int o = 0; o < 4; ++o) {
    #pragma unroll
    for (int i = 0; i < 4; ++i) {
      float wr = 0.f, wi = 0.f;
      #pragma unroll
      for (int l = 0; l < 4; ++l) {
        const int kl = ((o >> 1) << 3) | (l << 1) | (o & 1);
        wr = fmaf(hr[i * 4 + l], vr[kl], fmaf(-hi[i * 4 + l], vi[kl], wr));
        wi = fmaf(hr[i * 4 + l], vi[kl], fmaf(hi[i * 4 + l], vr[kl], wi));
      }
      const int ki = ((o >> 1) << 3) | (i << 1) | (o & 1);
      acc = fmaf(vr[ki], wr, fmaf(vi[ki], wi, acc));
    }
  }
  return acc;
}
__device__ __forceinline__ float obs_q10(const float2* __restrict__ hp,
                                         const float vr[16], const float vi[16]) {
  float hr[16], hi[16];
  #pragma unroll
  for (int i = 0; i < 16; ++i) { hr[i] = rfl(hp[i].x); hi[i] = rfl(hp[i].y); }
  float acc = 0.f;
  #pragma unroll
  for (int o = 0; o < 4; ++o) {
    #pragma unroll
    for (int i = 0; i < 4; ++i) {
      float wr = 0.f, wi = 0.f;
      #pragma unroll
      for (int l = 0; l < 4; ++l) {
        const int kl = (o << 2) | l;
        wr = fmaf(hr[i * 4 + l], vr[kl], fmaf(-hi[i * 4 + l], vi[kl], wr));
        wi = fmaf(hr[i * 4 + l], vi[kl], fmaf(hi[i * 4 + l], vr[kl], wi));
      }
      const int ki = (o << 2) | i;
      acc = fmaf(vr[ki], wr, fmaf(vi[ki], wi, acc));
    }
  }
  return acc;
}

__launch_bounds__(TCIRC)
__global__ void circuit_kernel(const float2* __restrict__ Umats,
                               const float* __restrict__ vp,
                               const float* __restrict__ oA,
                               const float* __restrict__ oB,
                               const float* __restrict__ oD,
                               float* __restrict__ out) {
  __shared__ float stR[DIM];                 // 64 KiB
  __shared__ float stI[DIM];                 // 64 KiB
  __shared__ float2 Ush[NGATES * 16];
  __shared__ float2 Hsh[NOBSN * 16];
  __shared__ float  ryc[DEPTHN * NQ];
  __shared__ float  rys[DEPTHN * NQ];
  __shared__ float  red[NOBSN][TCIRC / 64];

  const int b = blockIdx.x;
  const int tid = threadIdx.x;

  for (int i = tid; i < NGATES * 16; i += TCIRC)
    Ush[i] = Umats[b * NGATES * 16 + i];
  for (int i = tid; i < DEPTHN * NQ; i += TCIRC) {
    const float h = 0.5f * vp[i];
    ryc[i] = cosf(h);
    rys[i] = sinf(h);
  }
  if (tid < NOBSN) {
    const int rr[6] = {1, 2, 2, 3, 3, 3};
    const int cc[6] = {0, 0, 1, 0, 1, 2};
    float2 H[16];
    #pragma unroll
    for (int i = 0; i < 16; ++i) H[i] = make_float2(0.f, 0.f);
    for (int m = 0; m < 6; ++m) {
      const float a = oA[tid * 6 + m], bb = oB[tid * 6 + m];
      H[rr[m] * 4 + cc[m]] = make_float2(a, bb);
      H[cc[m] * 4 + rr[m]] = make_float2(a, -bb);
    }
    H[0]  = make_float2(2.f * oD[tid * 4 + 1], 0.f);
    H[5]  = make_float2(2.f * oD[tid * 4 + 2], 0.f);
    H[10] = make_float2(2.f * oD[tid * 4 + 3], 0.f);
    for (int i = 0; i < 16; ++i) Hsh[tid * 16 + i] = H[i];
  }
  for (int y = tid; y < DIM; y += TCIRC) {
    stR[y] = (y == 0) ? 1.f : 0.f;   // E(0)==0
    stI[y] = 0.f;
  }
  __syncthreads();

  // ---- SU(4) brick layer: gate idx g for even q=2m -> m, odd q=2m+1 -> 7+m
  su4_pass<10, 0,  1>(stR, stI, Ush, tid);   // q0 (bits 13,12), q2 (11,10)
  su4_pass< 6, 2,  3>(stR, stI, Ush, tid);   // q4 (9,8),  q6 (7,6)
  su4_pass< 2, 4,  5>(stR, stI, Ush, tid);   // q8 (5,4),  q10 (3,2)
  su4_pass< 0,-1,  6>(stR, stI, Ush, tid);   // q12 (1,0)
  su4_pass< 9, 7,  8>(stR, stI, Ush, tid);   // q1 (12,11), q3 (10,9)
  su4_pass< 5, 9, 10>(stR, stI, Ush, tid);   // q5 (8,7),  q7 (6,5)
  su4_pass< 1,11, 12>(stR, stI, Ush, tid);   // q9 (4,3),  q11 (2,1)

  // ---- variational depths; CNOT chain folded into next pass's reads ----
  ry_pass<10, false, 4>(stR, stI, ryc, rys, tid, 0);
  ry_pass< 6, false, 4>(stR, stI, ryc, rys, tid, 0);
  ry_pass< 2, false, 4>(stR, stI, ryc, rys, tid, 0);
  ry_pass< 0, false, 2>(stR, stI, ryc, rys, tid, 0);
  #pragma unroll 1
  for (int d = 1; d < DEPTHN; ++d) {
    ry_pass<10, true , 4>(stR, stI, ryc, rys, tid, d);  // carries perm of d-1
    ry_pass< 6, false, 4>(stR, stI, ryc, rys, tid, d);
    ry_pass< 2, false, 4>(stR, stI, ryc, rys, tid, d);
    ry_pass< 0, false, 2>(stR, stI, ryc, rys, tid, d);
  }

  // ---- observables: state in LDS is pre-perm of depth 3 -> all reads folded
  float oacc[NOBSN];
  {
    float vr[16], vi[16];
    load16<10, true>(stR, stI, tid, vr, vi);
    oacc[0] = obs_q32(Hsh + 0 * 16, vr, vi);   // bits (13,12)
    oacc[1] = obs_q21(Hsh + 1 * 16, vr, vi);   // (12,11)
    oacc[2] = obs_q10(Hsh + 2 * 16, vr, vi);   // (11,10)
  }
  {
    float vr[16], vi[16];
    load16<7, true>(stR, stI, tid, vr, vi);
    oacc[3] = obs_q32(Hsh + 3 * 16, vr, vi);   // (10,9)
    oacc[4] = obs_q21(Hsh + 4 * 16, vr, vi);   // (9,8)
    oacc[5] = obs_q10(Hsh + 5 * 16, vr, vi);   // (8,7)
  }
  {
    float vr[16], vi[16];
    load16<4, true>(stR, stI, tid, vr, vi);
    oacc[6] = obs_q32(Hsh + 6 * 16, vr, vi);   // (7,6)
    oacc[7] = obs_q21(Hsh + 7 * 16, vr, vi);   // (6,5)
    oacc[8] = obs_q10(Hsh + 8 * 16, vr, vi);   // (5,4)
  }
  {
    float vr[16], vi[16];
    load16<1, true>(stR, stI, tid, vr, vi);
    oacc[9]  = obs_q32(Hsh + 9 * 16, vr, vi);  // (4,3)
    oacc[10] = obs_q21(Hsh + 10 * 16, vr, vi); // (3,2)
    oacc[11] = obs_q10(Hsh + 11 * 16, vr, vi); // (2,1)
  }
  {
    float vr[16], vi[16];
    load16<0, true>(stR, stI, tid, vr, vi);
    oacc[12] = obs_q10(Hsh + 12 * 16, vr, vi); // (1,0)
  }

  const int lane = tid & 63, wid = tid >> 6;
  #pragma unroll
  for (int o = 0; o < NOBSN; ++o) {
    float a = oacc[o];
    #pragma unroll
    for (int off = 32; off > 0; off >>= 1)
      a += __shfl_down(a, off, 64);
    if (lane == 0) red[o][wid] = a;
  }
  __syncthreads();
  if (tid < NOBSN) {
    float s = 0.f;
    #pragma unroll
    for (int w = 0; w < TCIRC / 64; ++w) s += red[tid][w];
    out[b * NOBSN + tid] = s;
  }
}

extern "C" void kernel_launch(void* const* d_in, const int* in_sizes, int n_in,
                              void* d_out, int out_size, void* d_ws, size_t ws_size,
                              hipStream_t stream) {
  const float* x  = (const float*)d_in[0];
  const float* W1 = (const float*)d_in[1];
  const float* b1 = (const float*)d_in[2];
  const float* W2 = (const float*)d_in[3];
  const float* b2 = (const float*)d_in[4];
  const float* vp = (const float*)d_in[5];
  const float* oA = (const float*)d_in[6];
  const float* oB = (const float*)d_in[7];
  const float* oD = (const float*)d_in[8];
  float* out = (float*)d_out;

  float* enc = (float*)d_ws;
  const size_t enc_bytes = (size_t)BATCHN * ENCDIM * sizeof(float);
  float2* U = (float2*)((char*)d_ws + ((enc_bytes + 255) & ~(size_t)255));

  encoder_kernel<<<BATCHN, 256, 0, stream>>>(x, W1, b1, W2, b2, enc);
  build_u_kernel<<<(BATCHN * NGATES + 255) / 256, 256, 0, stream>>>(enc, U);
  circuit_kernel<<<BATCHN, TCIRC, 0, stream>>>(U, vp, oA, oB, oD, out);
}